// Round 14
// baseline (246860.034 us; speedup 1.0000x reference)
//
#include <hip/hip_runtime.h>
#include <math.h>

typedef unsigned long long u64;

#define TILE 2048
#define CAP 96
#define QB 32
#define NCELL 4096

// ---------------------------------------------------------------- helpers
__device__ __forceinline__ u64 wave_min_u64(u64 v) {
#pragma unroll
  for (int off = 32; off; off >>= 1) {
    u64 o = __shfl_xor(v, off, 64);
    v = (o < v) ? o : v;
  }
  return v;
}

__device__ __forceinline__ u64 wave_max_u64(u64 v) {
#pragma unroll
  for (int off = 32; off; off >>= 1) {
    u64 o = __shfl_xor(v, off, 64);
    v = (o > v) ? o : v;
  }
  return v;
}

__device__ __forceinline__ float angf(float ax, float ay, float az,
                                      float bx, float by, float bz) {
  float cx = ay * bz - az * by;
  float cy = az * bx - ax * bz;
  float cz = ax * by - ay * bx;
  float cn = sqrtf(cx * cx + cy * cy + cz * cz);
  float dt = ax * bx + ay * by + az * bz;
  return atan2f(cn, dt);
}

// Nested cell id: c = s*8 + m, supercell s = (cz>>1)<<6 | (cy>>1)<<3 | (cx>>1)
// (edge 4.0), member m = (cz&1)<<2 | (cy&1)<<1 | (cx&1) (edge 2.0).
// Lane l owns supercells [8l, 8l+8) -> cells [64l, 64l+64) -> their slots.
__device__ __forceinline__ int cell_of(float x, float y, float z) {
  int cx = (int)(x * 0.5f); cx = cx < 0 ? 0 : (cx > 15 ? 15 : cx);
  int cy = (int)(y * 0.5f); cy = cy < 0 ? 0 : (cy > 15 ? 15 : cy);
  int cz = (int)(z * 0.5f); cz = cz < 0 ? 0 : (cz > 15 ? 15 : cz);
  int s = ((cz >> 1) << 6) | ((cy >> 1) << 3) | (cx >> 1);
  int m = ((cz & 1) << 2) | ((cy & 1) << 1) | (cx & 1);
  return s * 8 + m;
}

// ---------------------------------------------------------------- lin_in
__global__ __launch_bounds__(256) void k_lin_in(
    const float* __restrict__ x, const float* __restrict__ w0,
    const float* __restrict__ b0, const float* __restrict__ w1,
    const float* __restrict__ b1, float* __restrict__ h) {
  __shared__ __align__(16) float sW0[1024];
  __shared__ __align__(16) float sW1[4096];
  __shared__ float sB0[64], sB1[64];
  for (int i = threadIdx.x; i < 1024; i += 256) sW0[i] = w0[i];
  for (int i = threadIdx.x; i < 4096; i += 256) sW1[i] = w1[i];
  if (threadIdx.x < 64) { sB0[threadIdx.x] = b0[threadIdx.x]; sB1[threadIdx.x] = b1[threadIdx.x]; }
  __syncthreads();
  int p = blockIdx.x * 256 + threadIdx.x;
  float h1[64];
#pragma unroll
  for (int o = 0; o < 64; ++o) h1[o] = sB0[o];
#pragma unroll
  for (int c4 = 0; c4 < 4; ++c4) {
    float4 xv = *(const float4*)&x[p * 16 + 4 * c4];
#pragma unroll
    for (int u = 0; u < 4; ++u) {
      float v = (u == 0) ? xv.x : (u == 1) ? xv.y : (u == 2) ? xv.z : xv.w;
      int c = 4 * c4 + u;
#pragma unroll
      for (int o4 = 0; o4 < 16; ++o4) {
        float4 w = *(const float4*)&sW0[c * 64 + 4 * o4];
        h1[4 * o4 + 0] = fmaf(v, w.x, h1[4 * o4 + 0]);
        h1[4 * o4 + 1] = fmaf(v, w.y, h1[4 * o4 + 1]);
        h1[4 * o4 + 2] = fmaf(v, w.z, h1[4 * o4 + 2]);
        h1[4 * o4 + 3] = fmaf(v, w.w, h1[4 * o4 + 3]);
      }
    }
  }
#pragma unroll
  for (int o = 0; o < 64; ++o) h1[o] = fmaxf(h1[o], 0.f);
  float h2[64];
#pragma unroll
  for (int o = 0; o < 64; ++o) h2[o] = sB1[o];
#pragma unroll
  for (int c = 0; c < 64; ++c) {
    float v = h1[c];
#pragma unroll
    for (int o4 = 0; o4 < 16; ++o4) {
      float4 w = *(const float4*)&sW1[c * 64 + 4 * o4];
      h2[4 * o4 + 0] = fmaf(v, w.x, h2[4 * o4 + 0]);
      h2[4 * o4 + 1] = fmaf(v, w.y, h2[4 * o4 + 1]);
      h2[4 * o4 + 2] = fmaf(v, w.z, h2[4 * o4 + 2]);
      h2[4 * o4 + 3] = fmaf(v, w.w, h2[4 * o4 + 3]);
    }
  }
#pragma unroll
  for (int o4 = 0; o4 < 16; ++o4) {
    float4 o;
    o.x = fmaxf(h2[4 * o4 + 0], 0.f);
    o.y = fmaxf(h2[4 * o4 + 1], 0.f);
    o.z = fmaxf(h2[4 * o4 + 2], 0.f);
    o.w = fmaxf(h2[4 * o4 + 3], 0.f);
    *(float4*)&h[(long)p * 64 + 4 * o4] = o;
  }
}

// --------------------------------------------- A = feat @ W0[:64,:] + b0
__global__ __launch_bounds__(256) void k_precompA(
    const float* __restrict__ feat, const float* __restrict__ w,
    const float* __restrict__ b, float* __restrict__ A, int n) {
  __shared__ __align__(16) float sW[4352];
  __shared__ float sB[68];
  for (int i = threadIdx.x; i < 4352; i += 256) sW[i] = w[i];
  for (int i = threadIdx.x; i < 68; i += 256) sB[i] = b[i];
  __syncthreads();
  int p = blockIdx.x * 256 + threadIdx.x;
  if (p >= n) return;
  float acc[68];
#pragma unroll
  for (int o = 0; o < 68; ++o) acc[o] = sB[o];
#pragma unroll
  for (int c4 = 0; c4 < 16; ++c4) {
    float4 f = *(const float4*)&feat[(long)p * 64 + 4 * c4];
#pragma unroll
    for (int u = 0; u < 4; ++u) {
      float v = (u == 0) ? f.x : (u == 1) ? f.y : (u == 2) ? f.z : f.w;
      int c = 4 * c4 + u;
#pragma unroll
      for (int o4 = 0; o4 < 17; ++o4) {
        float4 wv = *(const float4*)&sW[c * 68 + 4 * o4];
        acc[4 * o4 + 0] = fmaf(v, wv.x, acc[4 * o4 + 0]);
        acc[4 * o4 + 1] = fmaf(v, wv.y, acc[4 * o4 + 1]);
        acc[4 * o4 + 2] = fmaf(v, wv.z, acc[4 * o4 + 2]);
        acc[4 * o4 + 3] = fmaf(v, wv.w, acc[4 * o4 + 3]);
      }
    }
  }
#pragma unroll
  for (int o4 = 0; o4 < 17; ++o4) {
    float4 o;
    o.x = acc[4 * o4 + 0]; o.y = acc[4 * o4 + 1];
    o.z = acc[4 * o4 + 2]; o.w = acc[4 * o4 + 3];
    *(float4*)&A[(long)p * 68 + 4 * o4] = o;
  }
}

// ---------------------------------------------------------------- cell prep
__global__ __launch_bounds__(256) void k_zero_counts(int* __restrict__ c) {
  int i = blockIdx.x * 256 + threadIdx.x;
  if (i < NCELL) c[i] = 0;
}

__global__ __launch_bounds__(256) void k_hist(const float* __restrict__ pos,
                                              int n, int* __restrict__ counts) {
  int i = blockIdx.x * 256 + threadIdx.x;
  if (i >= n) return;
  atomicAdd(&counts[cell_of(pos[3 * i], pos[3 * i + 1], pos[3 * i + 2])], 1);
}

__global__ __launch_bounds__(512) void k_scan(const int* __restrict__ counts,
                                              int* __restrict__ starts,
                                              int* __restrict__ offs) {
  __shared__ int ps[512];
  int t = threadIdx.x;
  int loc[8], s = 0;
#pragma unroll
  for (int k = 0; k < 8; ++k) { loc[k] = counts[t * 8 + k]; s += loc[k]; }
  ps[t] = s;
  __syncthreads();
  for (int off = 1; off < 512; off <<= 1) {
    int v = (t >= off) ? ps[t - off] : 0;
    __syncthreads();
    ps[t] += v;
    __syncthreads();
  }
  int run = ps[t] - s;
#pragma unroll
  for (int k = 0; k < 8; ++k) {
    starts[t * 8 + k] = run;
    offs[t * 8 + k] = run;
    run += loc[k];
  }
  if (t == 511) starts[NCELL] = run;
}

__global__ __launch_bounds__(256) void k_scatter(
    const float* __restrict__ pos, int n, int* __restrict__ offs,
    float4* __restrict__ pts, int* __restrict__ sid, int* __restrict__ slot0) {
  int i = blockIdx.x * 256 + threadIdx.x;
  if (i >= n) return;
  float x = pos[3 * i], y = pos[3 * i + 1], z = pos[3 * i + 2];
  int c = cell_of(x, y, z);
  int slot = atomicAdd(&offs[c], 1);
  pts[slot] = make_float4(x, y, z, 3.402823466e38f);
  sid[slot] = i;
  if (i == 0) *slot0 = slot;
}

// ---------------------------------------------------------------- FPS (single wave)
// ONE wave (64 lanes), ZERO barriers in the main loop. Lane l exclusively
// owns supercells [8l,8l+8) = cells [64l,64l+64) = their slot ranges, so
// ck[] and pts[].w have a single writer AND single reader (no races).
// Per iteration:
//  1) 8 supercell box tests on register keys skreg[0..8] (fully unrolled,
//     static indexing) -> survivor bitmask; sparse-walk via __ffs.
//  2) surviving supercells: member-cell box test (own ck LDS read); on
//     survival re-scan the cell's points (8-wide clamped loads -> one L2
//     latency per cell; duplicate processing of the last point is
//     idempotent), ALWAYS rewrite ck + winner xyz (no stale keys).
//  3) dirty supercells refresh skreg from their 8 ck (unrolled).
//  4) 64-lane shuffle argmax (6 steps) -> winner cell known to all lanes.
//  5) __threadfence_block, then broadcast-read winner xyz from LDS.
// Keys: dr_bits<<32 | (32767-origIdx)<<12 | cell -> smallest original
// index on ties, matching jnp.argmax. Prune margin 0.9999 conservative;
// skipped points provably unchanged (mind >= drmax >= dr).
__global__ __launch_bounds__(64) void k_fps_wave(
    float4* __restrict__ pts, const int* __restrict__ sid,
    const int* __restrict__ starts, const int* __restrict__ slot0, int m,
    int* __restrict__ sel) {
#pragma clang fp contract(off)
  __shared__ u64 ck[NCELL];
  __shared__ int cs[NCELL + 1];
  __shared__ float bxS[NCELL], byS[NCELL], bzS[NCELL];
  const int lane = threadIdx.x;
  for (int c = lane; c < NCELL + 1; c += 64) cs[c] = starts[c];
  __syncthreads();
  for (int c = lane; c < NCELL; c += 64)
    ck[c] = (cs[c + 1] > cs[c]) ? ((u64)0x7F7FFFFFu << 32) : 0ull;
  u64 skreg[8];
#pragma unroll
  for (int q = 0; q < 8; ++q) {
    int cb = (lane * 8 + q) * 8;
    skreg[q] = (cs[cb + 8] > cs[cb]) ? ((u64)0x7F7FFFFFu << 32) : 0ull;
  }
  const float scy = (float)((lane & 7) * 4 + 2);
  const float scz = (float)((lane >> 3) * 4 + 2);
  if (lane == 0) sel[0] = 0;
  __syncthreads();
  float4 cp = pts[*slot0];
  float px = cp.x, py = cp.y, pz = cp.z;
  for (int i = 1; i < m; ++i) {
    // ---- 1) supercell tests (static regs -> bitmask)
    int smask = 0;
#pragma unroll
    for (int q = 0; q < 8; ++q) {
      float scx = (float)(q * 4 + 2);
      float dxs = fmaxf(fabsf(px - scx) - 2.f, 0.f);
      float dys = fmaxf(fabsf(py - scy) - 2.f, 0.f);
      float dzs = fmaxf(fabsf(pz - scz) - 2.f, 0.f);
      float m2s = (dxs * dxs + dys * dys) + dzs * dzs;
      if (__float_as_uint(m2s * 0.9999f) < (unsigned)(skreg[q] >> 32))
        smask |= 1 << q;
    }
    // ---- 2) process surviving supercells (sparse walk)
    int dmask = 0;
    while (smask) {
      int q = __ffs(smask) - 1;
      smask &= smask - 1;
      float scx = (float)(q * 4 + 2);
#pragma unroll 1
      for (int mm = 0; mm < 8; ++mm) {
        int c = (lane * 8 + q) * 8 + mm;
        unsigned ch = (unsigned)(ck[c] >> 32);
        float cxm = scx + ((mm & 1) ? 1.f : -1.f);
        float cym = scy + ((mm & 2) ? 1.f : -1.f);
        float czm = scz + ((mm & 4) ? 1.f : -1.f);
        float ex = fmaxf(fabsf(px - cxm) - 1.f, 0.f);
        float ey = fmaxf(fabsf(py - cym) - 1.f, 0.f);
        float ez = fmaxf(fabsf(pz - czm) - 1.f, 0.f);
        float m2 = (ex * ex + ey * ey) + ez * ez;
        if (__float_as_uint(m2 * 0.9999f) >= ch) continue;
        int s0 = cs[c], e0 = cs[c + 1];
        u64 best = 0;
        float lx = 0.f, ly = 0.f, lz = 0.f;
        for (int base = s0; base < e0; base += 8) {
          int e1 = e0 - 1;
          int i0 = base;
          int i1 = base + 1 < e0 ? base + 1 : e1;
          int i2 = base + 2 < e0 ? base + 2 : e1;
          int i3 = base + 3 < e0 ? base + 3 : e1;
          int i4 = base + 4 < e0 ? base + 4 : e1;
          int i5 = base + 5 < e0 ? base + 5 : e1;
          int i6 = base + 6 < e0 ? base + 6 : e1;
          int i7 = base + 7 < e0 ? base + 7 : e1;
          float4 p0 = pts[i0], p1 = pts[i1], p2 = pts[i2], p3 = pts[i3];
          float4 p4 = pts[i4], p5 = pts[i5], p6 = pts[i6], p7 = pts[i7];
          int o0 = sid[i0], o1 = sid[i1], o2 = sid[i2], o3 = sid[i3];
          int o4 = sid[i4], o5 = sid[i5], o6 = sid[i6], o7 = sid[i7];
#define PROC(pp, ii, oo)                                                   \
  {                                                                        \
    float ax = pp.x - px, ay = pp.y - py, az = pp.z - pz;                  \
    float d = (ax * ax + ay * ay) + az * az;                               \
    float nd = fminf(pp.w, d);                                             \
    ((float*)&pts[ii])[3] = nd;                                            \
    u64 kk = ((u64)__float_as_uint(nd) << 32) |                            \
             ((u64)(unsigned)(32767 - oo) << 12) | (unsigned)c;            \
    if (kk > best) { best = kk; lx = pp.x; ly = pp.y; lz = pp.z; }         \
  }
          PROC(p0, i0, o0) PROC(p1, i1, o1) PROC(p2, i2, o2) PROC(p3, i3, o3)
          PROC(p4, i4, o4) PROC(p5, i5, o5) PROC(p6, i6, o6) PROC(p7, i7, o7)
#undef PROC
        }
        ck[c] = best;
        bxS[c] = lx; byS[c] = ly; bzS[c] = lz;
        dmask |= 1 << q;
      }
    }
    // ---- 3) refresh dirty skreg (unrolled, static indexing)
#pragma unroll
    for (int q = 0; q < 8; ++q) {
      if ((dmask >> q) & 1) {
        u64 sk = 0;
#pragma unroll
        for (int mm = 0; mm < 8; ++mm) {
          u64 v = ck[(lane * 8 + q) * 8 + mm];
          if (v > sk) sk = v;
        }
        skreg[q] = sk;
      }
    }
    // ---- 4) wave argmax
    u64 lanebest = 0;
#pragma unroll
    for (int q = 0; q < 8; ++q)
      if (skreg[q] > lanebest) lanebest = skreg[q];
    u64 best = wave_max_u64(lanebest);
    int cell = (int)(best & 0xFFF);
    if (lane == 0) sel[i] = 32767 - (int)((best >> 12) & 0x7FFF);
    // ---- 5) broadcast winner xyz (cross-lane LDS handoff)
    __threadfence_block();
    px = bxS[cell]; py = byS[cell]; pz = bzS[cell];
  }
}

// ---------------------------------------------------------------- gather
__global__ __launch_bounds__(256) void k_gather(
    const float* __restrict__ pos, const float* __restrict__ nrm,
    const int* __restrict__ sel, int m, float* __restrict__ opos,
    float* __restrict__ onrm) {
  int i = blockIdx.x * 256 + threadIdx.x;
  if (i >= m) return;
  int s = sel[i];
  opos[3 * i + 0] = pos[3 * s + 0];
  opos[3 * i + 1] = pos[3 * s + 1];
  opos[3 * i + 2] = pos[3 * s + 2];
  onrm[3 * i + 0] = nrm[3 * s + 0];
  onrm[3 * i + 1] = nrm[3 * s + 1];
  onrm[3 * i + 2] = nrm[3 * s + 2];
}

// ---------------------------------------------------------------- conv
// Per block: 32 queries. Phase 1: exact (top-32 within radius) KNN via
// threshold-filtered candidate buffers. Phase 2: message MLP with layer 1
// fused into the layer-2 accumulation loop (no m1[68] array -> no scratch
// spill; R11 fix). 1-ahead Arow prefetch.
__global__ __launch_bounds__(512) void k_conv(
    const float* __restrict__ qpos, const float* __restrict__ qnorm, int nq,
    const float* __restrict__ dpos, const float* __restrict__ dnorm, int n,
    const float* __restrict__ A, const float* __restrict__ w0p,
    const float* __restrict__ w1g, const float* __restrict__ b1g,
    const float* __restrict__ w2g, const float* __restrict__ b2g, float r2,
    float* __restrict__ xout) {
  __shared__ __align__(16) float smem[12288];
  __shared__ float aggS[QB][68];
  __shared__ int knnS[QB][32];
  __shared__ float qpS[QB][3], qnS[QB][3];
  __shared__ __align__(16) float w0pS[272];
  __shared__ float b1S[68], b2S[64];

  const int tid = threadIdx.x, lane = tid & 63, wv = tid >> 6;
  const int q0 = blockIdx.x * QB;
  float* tileS = smem;
  u64* cand = (u64*)&smem[6144];

  for (int i = tid; i < QB * 3; i += 512) {
    ((float*)qpS)[i] = qpos[q0 * 3 + i];
    ((float*)qnS)[i] = qnorm[q0 * 3 + i];
  }
  for (int i = tid; i < 272; i += 512) {
    int o = i >> 2, f = i & 3;
    w0pS[i] = w0p[f * 68 + o];
  }
  for (int i = tid; i < 68; i += 512) b1S[i] = b1g[i];
  for (int i = tid; i < 64; i += 512) b2S[i] = b2g[i];
  __syncthreads();

  float qx[4], qy[4], qz[4], thr[4];
  int cnt[4], tight[4];
#pragma unroll
  for (int qi = 0; qi < 4; ++qi) {
    int ql = wv * 4 + qi;
    qx[qi] = qpS[ql][0]; qy[qi] = qpS[ql][1]; qz[qi] = qpS[ql][2];
    thr[qi] = r2; cnt[qi] = 0; tight[qi] = 0;
  }
  const u64 lmask = (1ull << lane) - 1ull;
  for (int t0 = 0; t0 < n; t0 += TILE) {
    __syncthreads();
    for (int i = tid; i < TILE * 3; i += 512) tileS[i] = dpos[t0 * 3 + i];
    __syncthreads();
    for (int s = 0; s < TILE; s += 64) {
      int p = s + lane;
      float px = tileS[3 * p], py = tileS[3 * p + 1], pz = tileS[3 * p + 2];
      int gidx = t0 + p;
#pragma unroll
      for (int qi = 0; qi < 4; ++qi) {
        float d2;
        {
#pragma clang fp contract(off)
          float ax = px - qx[qi], ay = py - qy[qi], az = pz - qz[qi];
          d2 = (ax * ax + ay * ay) + az * az;
        }
        bool pred = tight[qi] ? (d2 < thr[qi]) : (d2 <= thr[qi]);
        u64 mask = __ballot(pred);
        if (mask) {
          int need = __popcll(mask);
          int base = (wv * 4 + qi) * CAP;
          if (cnt[qi] + need > CAP) {
            u64 v0 = (lane < cnt[qi]) ? cand[base + lane] : ~0ull;
            u64 v1 = (lane + 64 < cnt[qi]) ? cand[base + lane + 64] : ~0ull;
            u64 keep = ~0ull, last = 0;
            for (int it = 0; it < 32; ++it) {
              u64 mloc = (v0 < v1) ? v0 : v1;
              u64 mn = wave_min_u64(mloc);
              if (lane == it) keep = mn;
              if (v0 == mn) v0 = ~0ull; else if (v1 == mn) v1 = ~0ull;
              last = mn;
            }
            if (lane < 32) cand[base + lane] = keep;
            cnt[qi] = 32;
            thr[qi] = __uint_as_float((unsigned)(last >> 32));
            tight[qi] = 1;
          }
          if (pred) {
            int slot = cnt[qi] + __popcll(mask & lmask);
            cand[base + slot] = ((u64)__float_as_uint(d2) << 32) | (unsigned)gidx;
          }
          cnt[qi] += need;
        }
      }
    }
  }
#pragma unroll
  for (int qi = 0; qi < 4; ++qi) {
    int ql = wv * 4 + qi, base = ql * CAP, c = cnt[qi];
    int nout = (c < 32) ? c : 32;
    u64 v0 = (lane < c) ? cand[base + lane] : ~0ull;
    u64 v1 = (lane + 64 < c) ? cand[base + lane + 64] : ~0ull;
    int first = 0;
    for (int it = 0; it < 32; ++it) {
      u64 mloc = (v0 < v1) ? v0 : v1;
      u64 mn = wave_min_u64(mloc);
      int idx = (int)(mn & 0xffffffffu);
      if (it == 0) first = idx;
      int wr = (it < nout) ? idx : first;
      if (lane == it) knnS[ql][it] = wr;
      if (it < nout) {
        if (v0 == mn) v0 = ~0ull; else if (v1 == mn) v1 = ~0ull;
      }
    }
  }
  __syncthreads();
  for (int i = tid; i < 4624; i += 512) smem[i] = w1g[i];
  for (int i = tid; i < 4352; i += 512) smem[4624 + i] = w2g[i];
  __syncthreads();
  const float* W1s = smem;
  const float* W2s = smem + 4624;

#pragma unroll 1
  for (int r = 0; r < 2; ++r) {
    const int h = lane >> 5;
    const int ql = r * 16 + wv * 2 + h;
    const int kk = lane & 31;
    const int j = knnS[ql][kk];
    const float qx_ = qpS[ql][0], qy_ = qpS[ql][1], qz_ = qpS[ql][2];
    float dx = dpos[3 * j + 0] - qx_;
    float dy = dpos[3 * j + 1] - qy_;
    float dz = dpos[3 * j + 2] - qz_;
    float f0 = sqrtf(dx * dx + dy * dy + dz * dz);
    float nix = qnS[ql][0], niy = qnS[ql][1], niz = qnS[ql][2];
    float njx = dnorm[3 * j + 0], njy = dnorm[3 * j + 1], njz = dnorm[3 * j + 2];
    float f1 = angf(nix, niy, niz, dx, dy, dz);
    float f2 = angf(njx, njy, njz, dx, dy, dz);
    float f3 = angf(nix, niy, niz, njx, njy, njz);
    const float* Arow = A + (long)j * 68;
    float acc[68];
#pragma unroll
    for (int o = 0; o < 68; ++o) acc[o] = b1S[o];
    float4 a = *(const float4*)&Arow[0];
#pragma unroll 1
    for (int c4 = 0; c4 < 17; ++c4) {
      float4 an = (c4 < 16) ? *(const float4*)&Arow[4 * (c4 + 1)] : a;
#pragma unroll
      for (int u = 0; u < 4; ++u) {
        int c = 4 * c4 + u;
        float4 wf = *(const float4*)&w0pS[4 * c];
        float v = (u == 0) ? a.x : (u == 1) ? a.y : (u == 2) ? a.z : a.w;
        v = fmaf(f0, wf.x, v);
        v = fmaf(f1, wf.y, v);
        v = fmaf(f2, wf.z, v);
        v = fmaf(f3, wf.w, v);
        float mv = fmaxf(v, 0.f);
#pragma unroll
        for (int o4 = 0; o4 < 17; ++o4) {
          float4 wv4 = *(const float4*)&W1s[c * 68 + 4 * o4];
          acc[4 * o4 + 0] = fmaf(mv, wv4.x, acc[4 * o4 + 0]);
          acc[4 * o4 + 1] = fmaf(mv, wv4.y, acc[4 * o4 + 1]);
          acc[4 * o4 + 2] = fmaf(mv, wv4.z, acc[4 * o4 + 2]);
          acc[4 * o4 + 3] = fmaf(mv, wv4.w, acc[4 * o4 + 3]);
        }
      }
      a = an;
    }
#pragma unroll
    for (int o = 0; o < 68; ++o) {
      float v = fmaxf(acc[o], 0.f);
#pragma unroll
      for (int off = 16; off; off >>= 1) v = fmaxf(v, __shfl_xor(v, off, 64));
      if (kk == 0) aggS[ql][o] = v;
    }
  }
  __syncthreads();
  {
    const int ql = tid >> 4;
    const int og = (tid & 15) * 4;
    float a0 = b2S[og + 0], a1 = b2S[og + 1], a2 = b2S[og + 2], a3 = b2S[og + 3];
#pragma unroll
    for (int c = 0; c < 68; ++c) {
      float av = aggS[ql][c];
      float4 wv4 = *(const float4*)&W2s[c * 64 + og];
      a0 = fmaf(av, wv4.x, a0);
      a1 = fmaf(av, wv4.y, a1);
      a2 = fmaf(av, wv4.z, a2);
      a3 = fmaf(av, wv4.w, a3);
    }
    float4 o;
    o.x = fmaxf(a0, 0.f); o.y = fmaxf(a1, 0.f);
    o.z = fmaxf(a2, 0.f); o.w = fmaxf(a3, 0.f);
    *(float4*)&xout[(long)(q0 + ql) * 64 + og] = o;
  }
}

// ---------------------------------------------------------------- final
__global__ __launch_bounds__(256) void k_final(
    const float* __restrict__ x3, const float* __restrict__ w0,
    const float* __restrict__ b0, const float* __restrict__ w1,
    const float* __restrict__ b1, float* __restrict__ out) {
  __shared__ float part[4][64];
  __shared__ float pooled[64];
  __shared__ float hS[64];
  int t = threadIdx.x, c = t & 63, g = t >> 6;
  float s = 0.f;
  for (int i = g; i < 4096; i += 4) s += x3[(long)i * 64 + c];
  part[g][c] = s;
  __syncthreads();
  if (t < 64)
    pooled[t] = (part[0][t] + part[1][t] + part[2][t] + part[3][t]) * (1.f / 4096.f);
  __syncthreads();
  if (t < 64) {
    float a = b0[t];
    for (int cc = 0; cc < 64; ++cc) a = fmaf(pooled[cc], w0[cc * 64 + t], a);
    hS[t] = fmaxf(a, 0.f);
  }
  __syncthreads();
  if (t < 2) {
    float a = b1[t];
    for (int cc = 0; cc < 64; ++cc) a = fmaf(hS[cc], w1[cc * 2 + t], a);
    out[t] = a;
  }
}

// ---------------------------------------------------------------- launch
extern "C" void kernel_launch(void* const* d_in, const int* in_sizes, int n_in,
                              void* d_out, int out_size, void* d_ws,
                              size_t ws_size, hipStream_t stream) {
  (void)in_sizes; (void)n_in; (void)out_size;
  const float* x     = (const float*)d_in[0];
  const float* pos   = (const float*)d_in[1];
  const float* nrm   = (const float*)d_in[2];
  const float* li_w0 = (const float*)d_in[3];
  const float* li_b0 = (const float*)d_in[4];
  const float* li_w1 = (const float*)d_in[5];
  const float* li_b1 = (const float*)d_in[6];
  const float* n1w0  = (const float*)d_in[7];   // [3][68][68]
  const float* n1b0  = (const float*)d_in[8];   // [3][68]
  const float* n1w1  = (const float*)d_in[9];   // [3][68][68]
  const float* n1b1  = (const float*)d_in[10];  // [3][68]
  const float* n2w   = (const float*)d_in[11];  // [3][68][64]
  const float* n2b   = (const float*)d_in[12];  // [3][64]
  const float* lo_w0 = (const float*)d_in[13];
  const float* lo_b0 = (const float*)d_in[14];
  const float* lo_w1 = (const float*)d_in[15];
  const float* lo_b1 = (const float*)d_in[16];
  float* out = (float*)d_out;

  char* ws = (char*)d_ws;
  size_t off = 0;
  auto alloc = [&](size_t nb) -> void* {
    void* p = (void*)(ws + off);
    off += nb;
    off = (off + 1023) & ~((size_t)1023);
    return p;
  };
  float* h     = (float*)alloc((size_t)32768 * 64 * 4);
  float* A0    = (float*)alloc((size_t)32768 * 68 * 4);
  int* counts  = (int*)  alloc((size_t)NCELL * 4);
  int* starts  = (int*)  alloc((size_t)(NCELL + 1) * 4);
  int* offs    = (int*)  alloc((size_t)NCELL * 4);
  float4* pts  = (float4*)alloc((size_t)32768 * 16);
  int* sid     = (int*)  alloc((size_t)32768 * 4);
  int* slot0   = (int*)  alloc((size_t)64);
  int*   sel0  = (int*)  alloc((size_t)16384 * 4);
  float* pos1  = (float*)alloc((size_t)16384 * 3 * 4);
  float* nrm1  = (float*)alloc((size_t)16384 * 3 * 4);
  float* x1    = (float*)alloc((size_t)16384 * 64 * 4);
  float* A1    = (float*)alloc((size_t)16384 * 68 * 4);
  int*   sel1  = (int*)  alloc((size_t)8192 * 4);
  float* pos2  = (float*)alloc((size_t)8192 * 3 * 4);
  float* nrm2  = (float*)alloc((size_t)8192 * 3 * 4);
  float* x2    = (float*)alloc((size_t)8192 * 64 * 4);
  float* A2    = (float*)alloc((size_t)8192 * 68 * 4);
  int*   sel2  = (int*)  alloc((size_t)4096 * 4);
  float* pos3  = (float*)alloc((size_t)4096 * 3 * 4);
  float* nrm3  = (float*)alloc((size_t)4096 * 3 * 4);
  float* x3    = (float*)alloc((size_t)4096 * 64 * 4);
  if (off > ws_size) return;  // workspace too small -> visible failure

  k_lin_in<<<128, 256, 0, stream>>>(x, li_w0, li_b0, li_w1, li_b1, h);
  k_precompA<<<128, 256, 0, stream>>>(h, n1w0, n1b0, A0, 32768);

  // level 0 FPS (n=32768 -> 16384)
  k_zero_counts<<<16, 256, 0, stream>>>(counts);
  k_hist<<<128, 256, 0, stream>>>(pos, 32768, counts);
  k_scan<<<1, 512, 0, stream>>>(counts, starts, offs);
  k_scatter<<<128, 256, 0, stream>>>(pos, 32768, offs, pts, sid, slot0);
  k_fps_wave<<<1, 64, 0, stream>>>(pts, sid, starts, slot0, 16384, sel0);
  k_gather<<<64, 256, 0, stream>>>(pos, nrm, sel0, 16384, pos1, nrm1);
  k_conv<<<512, 512, 0, stream>>>(pos1, nrm1, 16384, pos, nrm, 32768, A0,
                                  n1w0 + 64 * 68, n1w1, n1b1, n2w, n2b, 4.0f,
                                  x1);

  // level 1 FPS (n=16384 -> 8192)
  k_zero_counts<<<16, 256, 0, stream>>>(counts);
  k_hist<<<64, 256, 0, stream>>>(pos1, 16384, counts);
  k_scan<<<1, 512, 0, stream>>>(counts, starts, offs);
  k_scatter<<<64, 256, 0, stream>>>(pos1, 16384, offs, pts, sid, slot0);
  k_fps_wave<<<1, 64, 0, stream>>>(pts, sid, starts, slot0, 8192, sel1);
  k_gather<<<32, 256, 0, stream>>>(pos1, nrm1, sel1, 8192, pos2, nrm2);
  k_precompA<<<64, 256, 0, stream>>>(x1, n1w0 + 68 * 68, n1b0 + 68, A1, 16384);
  k_conv<<<256, 512, 0, stream>>>(pos2, nrm2, 8192, pos1, nrm1, 16384, A1,
                                  n1w0 + 68 * 68 + 64 * 68, n1w1 + 68 * 68,
                                  n1b1 + 68, n2w + 68 * 64, n2b + 64, 16.0f,
                                  x2);

  // level 2 FPS (n=8192 -> 4096)
  k_zero_counts<<<16, 256, 0, stream>>>(counts);
  k_hist<<<32, 256, 0, stream>>>(pos2, 8192, counts);
  k_scan<<<1, 512, 0, stream>>>(counts, starts, offs);
  k_scatter<<<32, 256, 0, stream>>>(pos2, 8192, offs, pts, sid, slot0);
  k_fps_wave<<<1, 64, 0, stream>>>(pts, sid, starts, slot0, 4096, sel2);
  k_gather<<<16, 256, 0, stream>>>(pos2, nrm2, sel2, 4096, pos3, nrm3);
  k_precompA<<<32, 256, 0, stream>>>(x2, n1w0 + 2 * 68 * 68, n1b0 + 2 * 68, A2,
                                     8192);
  k_conv<<<128, 512, 0, stream>>>(pos3, nrm3, 4096, pos2, nrm2, 8192, A2,
                                  n1w0 + 2 * 68 * 68 + 64 * 68,
                                  n1w1 + 2 * 68 * 68, n1b1 + 2 * 68,
                                  n2w + 2 * 68 * 64, n2b + 2 * 64, 64.0f, x3);
  k_final<<<1, 256, 0, stream>>>(x3, lo_w0, lo_b0, lo_w1, lo_b1, out);
}

// Round 15
// 54119.720 us; speedup vs baseline: 4.5614x; 4.5614x over previous
//
#include <hip/hip_runtime.h>
#include <math.h>

typedef unsigned long long u64;

#define TILE 2048
#define CAP 96
#define QB 32
#define NCELL 4096

// ---------------------------------------------------------------- helpers
__device__ __forceinline__ u64 wave_min_u64(u64 v) {
#pragma unroll
  for (int off = 32; off; off >>= 1) {
    u64 o = __shfl_xor(v, off, 64);
    v = (o < v) ? o : v;
  }
  return v;
}

__device__ __forceinline__ u64 wave_max_u64(u64 v) {
#pragma unroll
  for (int off = 32; off; off >>= 1) {
    u64 o = __shfl_xor(v, off, 64);
    v = (o > v) ? o : v;
  }
  return v;
}

__device__ __forceinline__ float angf(float ax, float ay, float az,
                                      float bx, float by, float bz) {
  float cx = ay * bz - az * by;
  float cy = az * bx - ax * bz;
  float cz = ax * by - ay * bx;
  float cn = sqrtf(cx * cx + cy * cy + cz * cz);
  float dt = ax * bx + ay * by + az * bz;
  return atan2f(cn, dt);
}

__device__ __forceinline__ int cell_of(float x, float y, float z) {
  int cx = (int)(x * 0.5f); cx = cx < 0 ? 0 : (cx > 15 ? 15 : cx);
  int cy = (int)(y * 0.5f); cy = cy < 0 ? 0 : (cy > 15 ? 15 : cy);
  int cz = (int)(z * 0.5f); cz = cz < 0 ? 0 : (cz > 15 ? 15 : cz);
  return (cz << 8) | (cy << 4) | cx;
}

// ---------------------------------------------------------------- lin_in
__global__ __launch_bounds__(256) void k_lin_in(
    const float* __restrict__ x, const float* __restrict__ w0,
    const float* __restrict__ b0, const float* __restrict__ w1,
    const float* __restrict__ b1, float* __restrict__ h) {
  __shared__ __align__(16) float sW0[1024];
  __shared__ __align__(16) float sW1[4096];
  __shared__ float sB0[64], sB1[64];
  for (int i = threadIdx.x; i < 1024; i += 256) sW0[i] = w0[i];
  for (int i = threadIdx.x; i < 4096; i += 256) sW1[i] = w1[i];
  if (threadIdx.x < 64) { sB0[threadIdx.x] = b0[threadIdx.x]; sB1[threadIdx.x] = b1[threadIdx.x]; }
  __syncthreads();
  int p = blockIdx.x * 256 + threadIdx.x;
  float h1[64];
#pragma unroll
  for (int o = 0; o < 64; ++o) h1[o] = sB0[o];
#pragma unroll
  for (int c4 = 0; c4 < 4; ++c4) {
    float4 xv = *(const float4*)&x[p * 16 + 4 * c4];
#pragma unroll
    for (int u = 0; u < 4; ++u) {
      float v = (u == 0) ? xv.x : (u == 1) ? xv.y : (u == 2) ? xv.z : xv.w;
      int c = 4 * c4 + u;
#pragma unroll
      for (int o4 = 0; o4 < 16; ++o4) {
        float4 w = *(const float4*)&sW0[c * 64 + 4 * o4];
        h1[4 * o4 + 0] = fmaf(v, w.x, h1[4 * o4 + 0]);
        h1[4 * o4 + 1] = fmaf(v, w.y, h1[4 * o4 + 1]);
        h1[4 * o4 + 2] = fmaf(v, w.z, h1[4 * o4 + 2]);
        h1[4 * o4 + 3] = fmaf(v, w.w, h1[4 * o4 + 3]);
      }
    }
  }
#pragma unroll
  for (int o = 0; o < 64; ++o) h1[o] = fmaxf(h1[o], 0.f);
  float h2[64];
#pragma unroll
  for (int o = 0; o < 64; ++o) h2[o] = sB1[o];
#pragma unroll
  for (int c = 0; c < 64; ++c) {
    float v = h1[c];
#pragma unroll
    for (int o4 = 0; o4 < 16; ++o4) {
      float4 w = *(const float4*)&sW1[c * 64 + 4 * o4];
      h2[4 * o4 + 0] = fmaf(v, w.x, h2[4 * o4 + 0]);
      h2[4 * o4 + 1] = fmaf(v, w.y, h2[4 * o4 + 1]);
      h2[4 * o4 + 2] = fmaf(v, w.z, h2[4 * o4 + 2]);
      h2[4 * o4 + 3] = fmaf(v, w.w, h2[4 * o4 + 3]);
    }
  }
#pragma unroll
  for (int o4 = 0; o4 < 16; ++o4) {
    float4 o;
    o.x = fmaxf(h2[4 * o4 + 0], 0.f);
    o.y = fmaxf(h2[4 * o4 + 1], 0.f);
    o.z = fmaxf(h2[4 * o4 + 2], 0.f);
    o.w = fmaxf(h2[4 * o4 + 3], 0.f);
    *(float4*)&h[(long)p * 64 + 4 * o4] = o;
  }
}

// --------------------------------------------- A = feat @ W0[:64,:] + b0
__global__ __launch_bounds__(256) void k_precompA(
    const float* __restrict__ feat, const float* __restrict__ w,
    const float* __restrict__ b, float* __restrict__ A, int n) {
  __shared__ __align__(16) float sW[4352];
  __shared__ float sB[68];
  for (int i = threadIdx.x; i < 4352; i += 256) sW[i] = w[i];
  for (int i = threadIdx.x; i < 68; i += 256) sB[i] = b[i];
  __syncthreads();
  int p = blockIdx.x * 256 + threadIdx.x;
  if (p >= n) return;
  float acc[68];
#pragma unroll
  for (int o = 0; o < 68; ++o) acc[o] = sB[o];
#pragma unroll
  for (int c4 = 0; c4 < 16; ++c4) {
    float4 f = *(const float4*)&feat[(long)p * 64 + 4 * c4];
#pragma unroll
    for (int u = 0; u < 4; ++u) {
      float v = (u == 0) ? f.x : (u == 1) ? f.y : (u == 2) ? f.z : f.w;
      int c = 4 * c4 + u;
#pragma unroll
      for (int o4 = 0; o4 < 17; ++o4) {
        float4 wv = *(const float4*)&sW[c * 68 + 4 * o4];
        acc[4 * o4 + 0] = fmaf(v, wv.x, acc[4 * o4 + 0]);
        acc[4 * o4 + 1] = fmaf(v, wv.y, acc[4 * o4 + 1]);
        acc[4 * o4 + 2] = fmaf(v, wv.z, acc[4 * o4 + 2]);
        acc[4 * o4 + 3] = fmaf(v, wv.w, acc[4 * o4 + 3]);
      }
    }
  }
#pragma unroll
  for (int o4 = 0; o4 < 17; ++o4) {
    float4 o;
    o.x = acc[4 * o4 + 0]; o.y = acc[4 * o4 + 1];
    o.z = acc[4 * o4 + 2]; o.w = acc[4 * o4 + 3];
    *(float4*)&A[(long)p * 68 + 4 * o4] = o;
  }
}

// ---------------------------------------------------------------- cell prep
__global__ __launch_bounds__(256) void k_zero_counts(int* __restrict__ c) {
  int i = blockIdx.x * 256 + threadIdx.x;
  if (i < NCELL) c[i] = 0;
}

__global__ __launch_bounds__(256) void k_hist(const float* __restrict__ pos,
                                              int n, int* __restrict__ counts) {
  int i = blockIdx.x * 256 + threadIdx.x;
  if (i >= n) return;
  atomicAdd(&counts[cell_of(pos[3 * i], pos[3 * i + 1], pos[3 * i + 2])], 1);
}

__global__ __launch_bounds__(512) void k_scan(const int* __restrict__ counts,
                                              int* __restrict__ starts,
                                              int* __restrict__ offs) {
  __shared__ int ps[512];
  int t = threadIdx.x;
  int loc[8], s = 0;
#pragma unroll
  for (int k = 0; k < 8; ++k) { loc[k] = counts[t * 8 + k]; s += loc[k]; }
  ps[t] = s;
  __syncthreads();
  for (int off = 1; off < 512; off <<= 1) {
    int v = (t >= off) ? ps[t - off] : 0;
    __syncthreads();
    ps[t] += v;
    __syncthreads();
  }
  int run = ps[t] - s;
#pragma unroll
  for (int k = 0; k < 8; ++k) {
    starts[t * 8 + k] = run;
    offs[t * 8 + k] = run;
    run += loc[k];
  }
  if (t == 511) starts[NCELL] = run;
}

__global__ __launch_bounds__(256) void k_scatter(
    const float* __restrict__ pos, int n, int* __restrict__ offs,
    float4* __restrict__ pts, int* __restrict__ sid, int* __restrict__ slot0) {
  int i = blockIdx.x * 256 + threadIdx.x;
  if (i >= n) return;
  float x = pos[3 * i], y = pos[3 * i + 1], z = pos[3 * i + 2];
  int c = cell_of(x, y, z);
  int slot = atomicAdd(&offs[c], 1);
  pts[slot] = make_float4(x, y, z, 3.402823466e38f);
  sid[slot] = i;
  if (i == 0) *slot0 = slot;
}

// ---------------------------------------------------------------- FPS (cell-pruned, R12-proven)
// Single block, 512 threads, 3 barriers/iter. Key = dr_bits<<32 |
// (32767-origIdx)<<12 | cell (smallest original index on ties, matching
// jnp.argmax; scatter order cannot matter). Phase A reads only the high
// 32-bit word of ck. Prune is safe: skipped cells have mind >= drmax >= dr
// for all their points (min() no-op); 0.9999 margin conservative.
// Phase B uses 8-lane groups over a shared survivor worklist -- this
// balances load (R14 showed spatial lane-ownership serializes on 1-4
// lanes at ~10us/iter).
__global__ __launch_bounds__(512) void k_fps_cell(
    float4* __restrict__ pts, const int* __restrict__ sid,
    const int* __restrict__ starts, const int* __restrict__ slot0, int m,
    int* __restrict__ sel) {
#pragma clang fp contract(off)
  __shared__ u64 ck[NCELL];
  __shared__ int cs[NCELL + 1];
  __shared__ unsigned short sl[NCELL];
  __shared__ float bx[NCELL], by[NCELL], bz[NCELL];
  __shared__ int scnt[2];
  __shared__ u64 wk[2][8];
  const int t = threadIdx.x, lane = t & 63, wv = t >> 6;
  const u64 lmask = (1ull << lane) - 1ull;
  const unsigned* ckhi = (const unsigned*)ck;  // [2c+1] = high word (LE)
  for (int c = t; c < NCELL + 1; c += 512) cs[c] = starts[c];
  __syncthreads();
  for (int c = t; c < NCELL; c += 512)
    ck[c] = (cs[c + 1] > cs[c]) ? ((u64)0x7F7FFFFFu << 32) : 0ull;
  if (t < 2) scnt[t] = 0;
  if (t == 0) sel[0] = 0;
  __syncthreads();
  float4 cp = pts[*slot0];
  float px = cp.x, py = cp.y, pz = cp.z;
  for (int i = 1; i < m; ++i) {
    const int par = i & 1;
    // -------- Phase A: prune cells (high-word drmax read only)
    bool sv[8];
#pragma unroll
    for (int k = 0; k < 8; ++k) {
      int c = t + 512 * k;
      unsigned drmax = ckhi[2 * c + 1];
      float cx = (float)(((c & 15) << 1) + 1);
      float cy = (float)((((c >> 4) & 15) << 1) + 1);
      float cz = (float)(((c >> 8) << 1) + 1);
      float dx = fmaxf(fabsf(px - cx) - 1.f, 0.f);
      float dy = fmaxf(fabsf(py - cy) - 1.f, 0.f);
      float dz = fmaxf(fabsf(pz - cz) - 1.f, 0.f);
      float mind2 = (dx * dx + dy * dy) + dz * dz;
      sv[k] = __float_as_uint(mind2 * 0.9999f) < drmax;
    }
    u64 msk[8];
    int wtot = 0;
#pragma unroll
    for (int k = 0; k < 8; ++k) {
      msk[k] = __ballot(sv[k]);
      wtot += __popcll(msk[k]);
    }
    int wbase = 0;
    if (lane == 0 && wtot) wbase = atomicAdd(&scnt[par], wtot);
    wbase = __shfl(wbase, 0, 64);
#pragma unroll
    for (int k = 0; k < 8; ++k) {
      if (sv[k])
        sl[wbase + __popcll(msk[k] & lmask)] = (unsigned short)(t + 512 * k);
      wbase += __popcll(msk[k]);
    }
    if (t == 0) scnt[par ^ 1] = 0;
    __syncthreads();  // b2: sl complete
    const int ns = scnt[par];
    // -------- Phase B: recompute survivor cells (8-lane groups)
    const int g0 = t >> 3, l = t & 7;
    for (int g = g0; g < ns; g += 64) {
      int c = sl[g];
      int s = cs[c], e = cs[c + 1];
      u64 lk = 0;
      float lx = 0.f, ly = 0.f, lz = 0.f;
      for (int slot = s + l; slot < e; slot += 8) {
        float4 p = pts[slot];
        float ax = p.x - px, ay = p.y - py, az = p.z - pz;
        float d = (ax * ax + ay * ay) + az * az;
        float nd = fminf(p.w, d);
        ((float*)&pts[slot])[3] = nd;
        int o = sid[slot];
        u64 kk = ((u64)__float_as_uint(nd) << 32) |
                 ((u64)(unsigned)(32767 - o) << 12) | (unsigned)c;
        if (kk > lk) { lk = kk; lx = p.x; ly = p.y; lz = p.z; }
      }
#pragma unroll
      for (int off = 4; off; off >>= 1) {
        u64 ok = __shfl_xor(lk, off, 64);
        float ox = __shfl_xor(lx, off, 64);
        float oy = __shfl_xor(ly, off, 64);
        float oz = __shfl_xor(lz, off, 64);
        if (ok > lk) { lk = ok; lx = ox; ly = oy; lz = oz; }
      }
      if (l == 0) {  // ALWAYS rewrite: keeps ck fresh (no stale winners)
        ck[c] = lk; bx[c] = lx; by[c] = ly; bz[c] = lz;
      }
    }
    __syncthreads();  // b3: ck/bxyz complete
    // -------- Phase C: argmax over cell keys
    u64 k = 0;
#pragma unroll
    for (int kk = 0; kk < 8; ++kk) {
      u64 v = ck[t + 512 * kk];
      if (v > k) k = v;
    }
    k = wave_max_u64(k);
    if (lane == 0) wk[par][wv] = k;
    __syncthreads();  // b4: wk complete
    u64 best = wk[par][0];
#pragma unroll
    for (int w = 1; w < 8; ++w) {
      u64 v = wk[par][w];
      if (v > best) best = v;
    }
    int cell = (int)(best & 0xFFF);
    if (t == 0) sel[i] = 32767 - (int)((best >> 12) & 0x7FFF);
    px = bx[cell]; py = by[cell]; pz = bz[cell];
  }
}

// ---------------------------------------------------------------- FPS L2 (brute, register-resident)
// R1-validated form: 512 threads, P=16 -> xr/yr/dr = 48 regs + temps fits
// the measured 128-VGPR budget of 512-thread kernels (single template
// instantiation to avoid R9's co-compile regalloc perturbation). z in LDS.
// One barrier/iter (parity-double-buffered wk); tie-break smallest index.
template <int P>
__global__ __launch_bounds__(512) void k_fps_breg(
    const float* __restrict__ pos, int n, int m, int* __restrict__ sel) {
#pragma clang fp contract(off)
  __shared__ float zb[512 * P];
  __shared__ u64 wk[2][8];
  const int t = threadIdx.x, lane = t & 63, wv = t >> 6;
  float xr[P], yr[P], dr[P];
#pragma unroll
  for (int j = 0; j < P; ++j) {
    int idx = t + 512 * j;
    xr[j] = pos[3 * idx + 0];
    yr[j] = pos[3 * idx + 1];
    zb[idx] = pos[3 * idx + 2];
    dr[j] = 3.402823466e38f;
  }
  if (t == 0) sel[0] = 0;
  __syncthreads();
  int cur = 0;
  for (int i = 1; i < m; ++i) {
    float px = pos[3 * cur + 0], py = pos[3 * cur + 1], pz = pos[3 * cur + 2];
    float bv = -1.f;
    int bi = 0;
#pragma unroll
    for (int j = 0; j < P; ++j) {
      int idx = t + 512 * j;
      float ax = xr[j] - px, ay = yr[j] - py, az = zb[idx] - pz;
      float d = (ax * ax + ay * ay) + az * az;
      float nd = fminf(dr[j], d);
      dr[j] = nd;
      if (nd > bv) { bv = nd; bi = idx; }
    }
#pragma unroll
    for (int off = 32; off; off >>= 1) {
      float ov = __shfl_xor(bv, off, 64);
      int oi = __shfl_xor(bi, off, 64);
      if (ov > bv || (ov == bv && oi < bi)) { bv = ov; bi = oi; }
    }
    int par = i & 1;
    if (lane == 0)
      wk[par][wv] = ((u64)__float_as_uint(bv) << 32) | (unsigned)(~bi);
    __syncthreads();
    u64 bk = wk[par][0];
#pragma unroll
    for (int w = 1; w < 8; ++w) {
      u64 o = wk[par][w];
      if (o > bk) bk = o;
    }
    cur = (int)(~(unsigned)bk);
    if (t == 0) sel[i] = cur;
  }
}

// ---------------------------------------------------------------- gather
__global__ __launch_bounds__(256) void k_gather(
    const float* __restrict__ pos, const float* __restrict__ nrm,
    const int* __restrict__ sel, int m, float* __restrict__ opos,
    float* __restrict__ onrm) {
  int i = blockIdx.x * 256 + threadIdx.x;
  if (i >= m) return;
  int s = sel[i];
  opos[3 * i + 0] = pos[3 * s + 0];
  opos[3 * i + 1] = pos[3 * s + 1];
  opos[3 * i + 2] = pos[3 * s + 2];
  onrm[3 * i + 0] = nrm[3 * s + 0];
  onrm[3 * i + 1] = nrm[3 * s + 1];
  onrm[3 * i + 2] = nrm[3 * s + 2];
}

// ---------------------------------------------------------------- conv
// Per block: 32 queries. Phase 1: exact (top-32 within radius) KNN via
// threshold-filtered candidate buffers. Phase 2: message MLP with layer 1
// fused into the layer-2 accumulation loop (no m1[68] array -> no scratch
// spill; R11 fix). 1-ahead Arow prefetch.
__global__ __launch_bounds__(512) void k_conv(
    const float* __restrict__ qpos, const float* __restrict__ qnorm, int nq,
    const float* __restrict__ dpos, const float* __restrict__ dnorm, int n,
    const float* __restrict__ A, const float* __restrict__ w0p,
    const float* __restrict__ w1g, const float* __restrict__ b1g,
    const float* __restrict__ w2g, const float* __restrict__ b2g, float r2,
    float* __restrict__ xout) {
  __shared__ __align__(16) float smem[12288];
  __shared__ float aggS[QB][68];
  __shared__ int knnS[QB][32];
  __shared__ float qpS[QB][3], qnS[QB][3];
  __shared__ __align__(16) float w0pS[272];
  __shared__ float b1S[68], b2S[64];

  const int tid = threadIdx.x, lane = tid & 63, wv = tid >> 6;
  const int q0 = blockIdx.x * QB;
  float* tileS = smem;
  u64* cand = (u64*)&smem[6144];

  for (int i = tid; i < QB * 3; i += 512) {
    ((float*)qpS)[i] = qpos[q0 * 3 + i];
    ((float*)qnS)[i] = qnorm[q0 * 3 + i];
  }
  for (int i = tid; i < 272; i += 512) {
    int o = i >> 2, f = i & 3;
    w0pS[i] = w0p[f * 68 + o];
  }
  for (int i = tid; i < 68; i += 512) b1S[i] = b1g[i];
  for (int i = tid; i < 64; i += 512) b2S[i] = b2g[i];
  __syncthreads();

  float qx[4], qy[4], qz[4], thr[4];
  int cnt[4], tight[4];
#pragma unroll
  for (int qi = 0; qi < 4; ++qi) {
    int ql = wv * 4 + qi;
    qx[qi] = qpS[ql][0]; qy[qi] = qpS[ql][1]; qz[qi] = qpS[ql][2];
    thr[qi] = r2; cnt[qi] = 0; tight[qi] = 0;
  }
  const u64 lmask = (1ull << lane) - 1ull;
  for (int t0 = 0; t0 < n; t0 += TILE) {
    __syncthreads();
    for (int i = tid; i < TILE * 3; i += 512) tileS[i] = dpos[t0 * 3 + i];
    __syncthreads();
    for (int s = 0; s < TILE; s += 64) {
      int p = s + lane;
      float px = tileS[3 * p], py = tileS[3 * p + 1], pz = tileS[3 * p + 2];
      int gidx = t0 + p;
#pragma unroll
      for (int qi = 0; qi < 4; ++qi) {
        float d2;
        {
#pragma clang fp contract(off)
          float ax = px - qx[qi], ay = py - qy[qi], az = pz - qz[qi];
          d2 = (ax * ax + ay * ay) + az * az;
        }
        bool pred = tight[qi] ? (d2 < thr[qi]) : (d2 <= thr[qi]);
        u64 mask = __ballot(pred);
        if (mask) {
          int need = __popcll(mask);
          int base = (wv * 4 + qi) * CAP;
          if (cnt[qi] + need > CAP) {
            u64 v0 = (lane < cnt[qi]) ? cand[base + lane] : ~0ull;
            u64 v1 = (lane + 64 < cnt[qi]) ? cand[base + lane + 64] : ~0ull;
            u64 keep = ~0ull, last = 0;
            for (int it = 0; it < 32; ++it) {
              u64 mloc = (v0 < v1) ? v0 : v1;
              u64 mn = wave_min_u64(mloc);
              if (lane == it) keep = mn;
              if (v0 == mn) v0 = ~0ull; else if (v1 == mn) v1 = ~0ull;
              last = mn;
            }
            if (lane < 32) cand[base + lane] = keep;
            cnt[qi] = 32;
            thr[qi] = __uint_as_float((unsigned)(last >> 32));
            tight[qi] = 1;
          }
          if (pred) {
            int slot = cnt[qi] + __popcll(mask & lmask);
            cand[base + slot] = ((u64)__float_as_uint(d2) << 32) | (unsigned)gidx;
          }
          cnt[qi] += need;
        }
      }
    }
  }
#pragma unroll
  for (int qi = 0; qi < 4; ++qi) {
    int ql = wv * 4 + qi, base = ql * CAP, c = cnt[qi];
    int nout = (c < 32) ? c : 32;
    u64 v0 = (lane < c) ? cand[base + lane] : ~0ull;
    u64 v1 = (lane + 64 < c) ? cand[base + lane + 64] : ~0ull;
    int first = 0;
    for (int it = 0; it < 32; ++it) {
      u64 mloc = (v0 < v1) ? v0 : v1;
      u64 mn = wave_min_u64(mloc);
      int idx = (int)(mn & 0xffffffffu);
      if (it == 0) first = idx;
      int wr = (it < nout) ? idx : first;
      if (lane == it) knnS[ql][it] = wr;
      if (it < nout) {
        if (v0 == mn) v0 = ~0ull; else if (v1 == mn) v1 = ~0ull;
      }
    }
  }
  __syncthreads();
  for (int i = tid; i < 4624; i += 512) smem[i] = w1g[i];
  for (int i = tid; i < 4352; i += 512) smem[4624 + i] = w2g[i];
  __syncthreads();
  const float* W1s = smem;
  const float* W2s = smem + 4624;

#pragma unroll 1
  for (int r = 0; r < 2; ++r) {
    const int h = lane >> 5;
    const int ql = r * 16 + wv * 2 + h;
    const int kk = lane & 31;
    const int j = knnS[ql][kk];
    const float qx_ = qpS[ql][0], qy_ = qpS[ql][1], qz_ = qpS[ql][2];
    float dx = dpos[3 * j + 0] - qx_;
    float dy = dpos[3 * j + 1] - qy_;
    float dz = dpos[3 * j + 2] - qz_;
    float f0 = sqrtf(dx * dx + dy * dy + dz * dz);
    float nix = qnS[ql][0], niy = qnS[ql][1], niz = qnS[ql][2];
    float njx = dnorm[3 * j + 0], njy = dnorm[3 * j + 1], njz = dnorm[3 * j + 2];
    float f1 = angf(nix, niy, niz, dx, dy, dz);
    float f2 = angf(njx, njy, njz, dx, dy, dz);
    float f3 = angf(nix, niy, niz, njx, njy, njz);
    const float* Arow = A + (long)j * 68;
    float acc[68];
#pragma unroll
    for (int o = 0; o < 68; ++o) acc[o] = b1S[o];
    float4 a = *(const float4*)&Arow[0];
#pragma unroll 1
    for (int c4 = 0; c4 < 17; ++c4) {
      float4 an = (c4 < 16) ? *(const float4*)&Arow[4 * (c4 + 1)] : a;
#pragma unroll
      for (int u = 0; u < 4; ++u) {
        int c = 4 * c4 + u;
        float4 wf = *(const float4*)&w0pS[4 * c];
        float v = (u == 0) ? a.x : (u == 1) ? a.y : (u == 2) ? a.z : a.w;
        v = fmaf(f0, wf.x, v);
        v = fmaf(f1, wf.y, v);
        v = fmaf(f2, wf.z, v);
        v = fmaf(f3, wf.w, v);
        float mv = fmaxf(v, 0.f);
#pragma unroll
        for (int o4 = 0; o4 < 17; ++o4) {
          float4 wv4 = *(const float4*)&W1s[c * 68 + 4 * o4];
          acc[4 * o4 + 0] = fmaf(mv, wv4.x, acc[4 * o4 + 0]);
          acc[4 * o4 + 1] = fmaf(mv, wv4.y, acc[4 * o4 + 1]);
          acc[4 * o4 + 2] = fmaf(mv, wv4.z, acc[4 * o4 + 2]);
          acc[4 * o4 + 3] = fmaf(mv, wv4.w, acc[4 * o4 + 3]);
        }
      }
      a = an;
    }
#pragma unroll
    for (int o = 0; o < 68; ++o) {
      float v = fmaxf(acc[o], 0.f);
#pragma unroll
      for (int off = 16; off; off >>= 1) v = fmaxf(v, __shfl_xor(v, off, 64));
      if (kk == 0) aggS[ql][o] = v;
    }
  }
  __syncthreads();
  {
    const int ql = tid >> 4;
    const int og = (tid & 15) * 4;
    float a0 = b2S[og + 0], a1 = b2S[og + 1], a2 = b2S[og + 2], a3 = b2S[og + 3];
#pragma unroll
    for (int c = 0; c < 68; ++c) {
      float av = aggS[ql][c];
      float4 wv4 = *(const float4*)&W2s[c * 64 + og];
      a0 = fmaf(av, wv4.x, a0);
      a1 = fmaf(av, wv4.y, a1);
      a2 = fmaf(av, wv4.z, a2);
      a3 = fmaf(av, wv4.w, a3);
    }
    float4 o;
    o.x = fmaxf(a0, 0.f); o.y = fmaxf(a1, 0.f);
    o.z = fmaxf(a2, 0.f); o.w = fmaxf(a3, 0.f);
    *(float4*)&xout[(long)(q0 + ql) * 64 + og] = o;
  }
}

// ---------------------------------------------------------------- final
__global__ __launch_bounds__(256) void k_final(
    const float* __restrict__ x3, const float* __restrict__ w0,
    const float* __restrict__ b0, const float* __restrict__ w1,
    const float* __restrict__ b1, float* __restrict__ out) {
  __shared__ float part[4][64];
  __shared__ float pooled[64];
  __shared__ float hS[64];
  int t = threadIdx.x, c = t & 63, g = t >> 6;
  float s = 0.f;
  for (int i = g; i < 4096; i += 4) s += x3[(long)i * 64 + c];
  part[g][c] = s;
  __syncthreads();
  if (t < 64)
    pooled[t] = (part[0][t] + part[1][t] + part[2][t] + part[3][t]) * (1.f / 4096.f);
  __syncthreads();
  if (t < 64) {
    float a = b0[t];
    for (int cc = 0; cc < 64; ++cc) a = fmaf(pooled[cc], w0[cc * 64 + t], a);
    hS[t] = fmaxf(a, 0.f);
  }
  __syncthreads();
  if (t < 2) {
    float a = b1[t];
    for (int cc = 0; cc < 64; ++cc) a = fmaf(hS[cc], w1[cc * 2 + t], a);
    out[t] = a;
  }
}

// ---------------------------------------------------------------- launch
extern "C" void kernel_launch(void* const* d_in, const int* in_sizes, int n_in,
                              void* d_out, int out_size, void* d_ws,
                              size_t ws_size, hipStream_t stream) {
  (void)in_sizes; (void)n_in; (void)out_size;
  const float* x     = (const float*)d_in[0];
  const float* pos   = (const float*)d_in[1];
  const float* nrm   = (const float*)d_in[2];
  const float* li_w0 = (const float*)d_in[3];
  const float* li_b0 = (const float*)d_in[4];
  const float* li_w1 = (const float*)d_in[5];
  const float* li_b1 = (const float*)d_in[6];
  const float* n1w0  = (const float*)d_in[7];   // [3][68][68]
  const float* n1b0  = (const float*)d_in[8];   // [3][68]
  const float* n1w1  = (const float*)d_in[9];   // [3][68][68]
  const float* n1b1  = (const float*)d_in[10];  // [3][68]
  const float* n2w   = (const float*)d_in[11];  // [3][68][64]
  const float* n2b   = (const float*)d_in[12];  // [3][64]
  const float* lo_w0 = (const float*)d_in[13];
  const float* lo_b0 = (const float*)d_in[14];
  const float* lo_w1 = (const float*)d_in[15];
  const float* lo_b1 = (const float*)d_in[16];
  float* out = (float*)d_out;

  char* ws = (char*)d_ws;
  size_t off = 0;
  auto alloc = [&](size_t nb) -> void* {
    void* p = (void*)(ws + off);
    off += nb;
    off = (off + 1023) & ~((size_t)1023);
    return p;
  };
  float* h     = (float*)alloc((size_t)32768 * 64 * 4);
  float* A0    = (float*)alloc((size_t)32768 * 68 * 4);
  int* counts  = (int*)  alloc((size_t)NCELL * 4);
  int* starts  = (int*)  alloc((size_t)(NCELL + 1) * 4);
  int* offs    = (int*)  alloc((size_t)NCELL * 4);
  float4* pts  = (float4*)alloc((size_t)32768 * 16);
  int* sid     = (int*)  alloc((size_t)32768 * 4);
  int* slot0   = (int*)  alloc((size_t)64);
  int*   sel0  = (int*)  alloc((size_t)16384 * 4);
  float* pos1  = (float*)alloc((size_t)16384 * 3 * 4);
  float* nrm1  = (float*)alloc((size_t)16384 * 3 * 4);
  float* x1    = (float*)alloc((size_t)16384 * 64 * 4);
  float* A1    = (float*)alloc((size_t)16384 * 68 * 4);
  int*   sel1  = (int*)  alloc((size_t)8192 * 4);
  float* pos2  = (float*)alloc((size_t)8192 * 3 * 4);
  float* nrm2  = (float*)alloc((size_t)8192 * 3 * 4);
  float* x2    = (float*)alloc((size_t)8192 * 64 * 4);
  float* A2    = (float*)alloc((size_t)8192 * 68 * 4);
  int*   sel2  = (int*)  alloc((size_t)4096 * 4);
  float* pos3  = (float*)alloc((size_t)4096 * 3 * 4);
  float* nrm3  = (float*)alloc((size_t)4096 * 3 * 4);
  float* x3    = (float*)alloc((size_t)4096 * 64 * 4);
  if (off > ws_size) return;  // workspace too small -> visible failure

  k_lin_in<<<128, 256, 0, stream>>>(x, li_w0, li_b0, li_w1, li_b1, h);
  k_precompA<<<128, 256, 0, stream>>>(h, n1w0, n1b0, A0, 32768);

  // level 0 FPS (n=32768 -> 16384)
  k_zero_counts<<<16, 256, 0, stream>>>(counts);
  k_hist<<<128, 256, 0, stream>>>(pos, 32768, counts);
  k_scan<<<1, 512, 0, stream>>>(counts, starts, offs);
  k_scatter<<<128, 256, 0, stream>>>(pos, 32768, offs, pts, sid, slot0);
  k_fps_cell<<<1, 512, 0, stream>>>(pts, sid, starts, slot0, 16384, sel0);
  k_gather<<<64, 256, 0, stream>>>(pos, nrm, sel0, 16384, pos1, nrm1);
  k_conv<<<512, 512, 0, stream>>>(pos1, nrm1, 16384, pos, nrm, 32768, A0,
                                  n1w0 + 64 * 68, n1w1, n1b1, n2w, n2b, 4.0f,
                                  x1);

  // level 1 FPS (n=16384 -> 8192)
  k_zero_counts<<<16, 256, 0, stream>>>(counts);
  k_hist<<<64, 256, 0, stream>>>(pos1, 16384, counts);
  k_scan<<<1, 512, 0, stream>>>(counts, starts, offs);
  k_scatter<<<64, 256, 0, stream>>>(pos1, 16384, offs, pts, sid, slot0);
  k_fps_cell<<<1, 512, 0, stream>>>(pts, sid, starts, slot0, 8192, sel1);
  k_gather<<<32, 256, 0, stream>>>(pos1, nrm1, sel1, 8192, pos2, nrm2);
  k_precompA<<<64, 256, 0, stream>>>(x1, n1w0 + 68 * 68, n1b0 + 68, A1, 16384);
  k_conv<<<256, 512, 0, stream>>>(pos2, nrm2, 8192, pos1, nrm1, 16384, A1,
                                  n1w0 + 68 * 68 + 64 * 68, n1w1 + 68 * 68,
                                  n1b1 + 68, n2w + 68 * 64, n2b + 64, 16.0f,
                                  x2);

  // level 2 FPS (n=8192 -> 4096): brute-force register kernel
  k_fps_breg<16><<<1, 512, 0, stream>>>(pos2, 8192, 4096, sel2);
  k_gather<<<16, 256, 0, stream>>>(pos2, nrm2, sel2, 4096, pos3, nrm3);
  k_precompA<<<32, 256, 0, stream>>>(x2, n1w0 + 2 * 68 * 68, n1b0 + 2 * 68, A2,
                                     8192);
  k_conv<<<128, 512, 0, stream>>>(pos3, nrm3, 4096, pos2, nrm2, 8192, A2,
                                  n1w0 + 2 * 68 * 68 + 64 * 68,
                                  n1w1 + 2 * 68 * 68, n1b1 + 2 * 68,
                                  n2w + 2 * 68 * 64, n2b + 2 * 64, 64.0f, x3);
  k_final<<<1, 256, 0, stream>>>(x3, lo_w0, lo_b0, lo_w1, lo_b1, out);
}